// Round 16
// baseline (240.165 us; speedup 1.0000x reference)
//
#include <hip/hip_runtime.h>

#define N_NODES 50000
#define N_EDGES 800000
#define DIM 128
#define N_LAYERS 3
#define N_GRAPHS 256
#define OUT_COLS (N_LAYERS * DIM)

#define SUBS 4
#define SUBCAP 24
#define ROWSTRIDE (SUBS * SUBCAP)  // 96 ushorts per node

// fused prep grid layout
#define FILL_NB 3125   // 800000 / 256
#define X2H_NB 6250    // (50000*128/4) / 256
#define WPREP_NB 384   // (2*3*128*128) / 256

typedef __attribute__((ext_vector_type(8))) _Float16 half8;
typedef __attribute__((ext_vector_type(4))) float f32x4;
typedef __attribute__((ext_vector_type(4))) unsigned short us4;
typedef __attribute__((ext_vector_type(8))) short short8;

// ---- fused prep: fill_sub | x2h | wprep, branch on blockIdx ----
__global__ __launch_bounds__(256) void prep_kernel(
        const int* __restrict__ src, const int* __restrict__ dst,
        int* __restrict__ deg4, unsigned short* __restrict__ elist,
        const float* __restrict__ x, unsigned short* __restrict__ x16,
        const float* __restrict__ W1, const float* __restrict__ W2,
        _Float16* __restrict__ Wt) {
    const int b = blockIdx.x;
    if (b < FILL_NB) {
        int e = b * 256 + threadIdx.x;
        int d = dst[e];
        int s = src[e];
        int sub = e & (SUBS - 1);
        int r = atomicAdd(&deg4[d * SUBS + sub], 1);
        if (r < SUBCAP) elist[(size_t)d * ROWSTRIDE + sub * SUBCAP + r] = (unsigned short)s;
    } else if (b < FILL_NB + X2H_NB) {
        int i = (b - FILL_NB) * 256 + threadIdx.x;  // one per 4 elements
        float4 v = *(const float4*)&x[(size_t)i * 4];
        us4 o;
        _Float16 h0 = (_Float16)v.x, h1 = (_Float16)v.y, h2 = (_Float16)v.z, h3 = (_Float16)v.w;
        o.x = *(unsigned short*)&h0; o.y = *(unsigned short*)&h1;
        o.z = *(unsigned short*)&h2; o.w = *(unsigned short*)&h3;
        *(us4*)&x16[(size_t)i * 4] = o;
    } else {
        int i = (b - FILL_NB - X2H_NB) * 256 + threadIdx.x;
        int which = i / (N_LAYERS * DIM * DIM);
        int rem = i % (N_LAYERS * DIM * DIM);
        int layer = rem / (DIM * DIM);
        int kj = rem % (DIM * DIM);
        int k = kj / DIM, j = kj % DIM;
        float w = (which ? W2 : W1)[rem];
        int lin = layer * 2 + which;
        Wt[(lin * DIM + j) * DIM + k] = (_Float16)w;  // transposed
    }
}

// ---- fused layer: gather (in A-frag layout, 4-edge unroll) -> MLP -> pool ----
// ONE WAVE per 16 nodes, barrier-free. Lane l owns row (l&15), dims (l>>4)*8+kb*32.
__global__ __launch_bounds__(64, 3) void fused_layer_kernel(
        const unsigned short* __restrict__ hin, const int* __restrict__ deg4,
        const unsigned short* __restrict__ elist,
        const _Float16* __restrict__ Wt,
        const float* __restrict__ bias1, const float* __restrict__ bias2,
        const int* __restrict__ batch, unsigned short* __restrict__ h16out,
        float* __restrict__ pool_out, int layer, int write_h) {
    __shared__ float S[16][132];
    __shared__ int gb[16];
    const int l = threadIdx.x;
    const int lr = l & 15;
    const int lk = l >> 4;
    const int row0 = blockIdx.x * 16;  // N_NODES = 16*3125 exactly

    if (l < 16) gb[l] = batch[row0 + l];

    // ---- gather phase: acc[kb][j] = agg[row=row0+lr][kb*32 + lk*8 + j] in fp32 ----
    const int node = row0 + lr;
    float acc[4][8];
    {
        const size_t sb = (size_t)node * DIM + lk * 8;
#pragma unroll
        for (int kb = 0; kb < 4; kb++) {
            half8 v = *(const half8*)&hin[sb + kb * 32];
#pragma unroll
            for (int j = 0; j < 8; j++) acc[kb][j] = (float)v[j];
        }
    }
    int4 c4 = *(const int4*)&deg4[node * SUBS];
    const unsigned short* elbase = &elist[(size_t)node * ROWSTRIDE];
#pragma unroll
    for (int sub = 0; sub < SUBS; sub++) {
        int cnt = ((const int*)&c4)[sub];
        if (cnt > SUBCAP) cnt = SUBCAP;
        const unsigned short* el = elbase + sub * SUBCAP;
        int i = 0;
        // 4-edge unroll: 16 independent 16B loads in flight before the accumulate
        for (; i + 4 <= cnt; i += 4) {
            int s0 = el[i], s1 = el[i + 1], s2 = el[i + 2], s3 = el[i + 3];
            const size_t b0 = (size_t)s0 * DIM + lk * 8;
            const size_t b1 = (size_t)s1 * DIM + lk * 8;
            const size_t b2 = (size_t)s2 * DIM + lk * 8;
            const size_t b3 = (size_t)s3 * DIM + lk * 8;
            half8 v0[4], v1[4], v2[4], v3[4];
#pragma unroll
            for (int kb = 0; kb < 4; kb++) {
                v0[kb] = *(const half8*)&hin[b0 + kb * 32];
                v1[kb] = *(const half8*)&hin[b1 + kb * 32];
                v2[kb] = *(const half8*)&hin[b2 + kb * 32];
                v3[kb] = *(const half8*)&hin[b3 + kb * 32];
            }
#pragma unroll
            for (int kb = 0; kb < 4; kb++)
#pragma unroll
                for (int j = 0; j < 8; j++)
                    acc[kb][j] += ((float)v0[kb][j] + (float)v1[kb][j]) +
                                  ((float)v2[kb][j] + (float)v3[kb][j]);
        }
        for (; i < cnt; i++) {
            int s0 = el[i];
            const size_t b0 = (size_t)s0 * DIM + lk * 8;
#pragma unroll
            for (int kb = 0; kb < 4; kb++) {
                half8 v0 = *(const half8*)&hin[b0 + kb * 32];
#pragma unroll
                for (int j = 0; j < 8; j++) acc[kb][j] += (float)v0[j];
            }
        }
    }
    // acc -> fp16 A-fragments (same rounding as the unfused agg path)
    half8 ah[4];
#pragma unroll
    for (int kb = 0; kb < 4; kb++)
#pragma unroll
        for (int j = 0; j < 8; j++) ah[kb][j] = (_Float16)acc[kb][j];

    // ---- linear1 -> relu -> S ----
#pragma unroll
    for (int cb = 0; cb < 8; cb++) {
        const _Float16* wp = &Wt[(cb * 16 + lr) * DIM + lk * 8];
        half8 w[4];
#pragma unroll
        for (int kb = 0; kb < 4; kb++) w[kb] = *(const half8*)&wp[kb * 32];
        f32x4 aA = {0.f, 0.f, 0.f, 0.f};
#pragma unroll
        for (int kb = 0; kb < 4; kb++)
            aA = __builtin_amdgcn_mfma_f32_16x16x32_f16(ah[kb], w[kb], aA, 0, 0, 0);
        float bv = bias1[cb * 16 + lr];
#pragma unroll
        for (int r = 0; r < 4; r++)
            S[lk * 4 + r][cb * 16 + lr] = fmaxf(aA[r] + bv, 0.f);
    }

    // ---- T -> A2 fragments (in-wave LDS exchange; split hi/lo for accuracy) ----
    half8 ch[4], cl[4];
#pragma unroll
    for (int kb = 0; kb < 4; kb++) {
        const float* sr = &S[lr][kb * 32 + lk * 8];
        f32x4 u0 = *(const f32x4*)&sr[0];
        f32x4 u1 = *(const f32x4*)&sr[4];
        float uu[8] = {u0.x, u0.y, u0.z, u0.w, u1.x, u1.y, u1.z, u1.w};
        half8 hh, ll;
#pragma unroll
        for (int j = 0; j < 8; j++) {
            _Float16 hv = (_Float16)uu[j];
            hh[j] = hv;
            ll[j] = (_Float16)(uu[j] - (float)hv);
        }
        ch[kb] = hh;
        cl[kb] = ll;
    }

    // ---- linear2 -> relu -> S ----
    const _Float16* W2 = Wt + DIM * DIM;
#pragma unroll
    for (int cb = 0; cb < 8; cb++) {
        const _Float16* wp = &W2[(cb * 16 + lr) * DIM + lk * 8];
        half8 w[4];
#pragma unroll
        for (int kb = 0; kb < 4; kb++) w[kb] = *(const half8*)&wp[kb * 32];
        f32x4 aA = {0.f, 0.f, 0.f, 0.f}, aC = aA;
#pragma unroll
        for (int kb = 0; kb < 4; kb++) {
            aA = __builtin_amdgcn_mfma_f32_16x16x32_f16(ch[kb], w[kb], aA, 0, 0, 0);
            aC = __builtin_amdgcn_mfma_f32_16x16x32_f16(cl[kb], w[kb], aC, 0, 0, 0);
        }
        float bv = bias2[cb * 16 + lr];
#pragma unroll
        for (int r = 0; r < 4; r++)
            S[lk * 4 + r][cb * 16 + lr] = fmaxf(aA[r] + aC[r] + bv, 0.f);
    }

    // ---- fp16 h write (from LDS; within-wave ordering) ----
    if (write_h) {
        const int r = l >> 2, c0 = (l & 3) * 32;
        unsigned short buf[32];
#pragma unroll
        for (int j = 0; j < 32; j++) {
            _Float16 hv = (_Float16)S[r][c0 + j];
            buf[j] = *(unsigned short*)&hv;
        }
        const size_t ob = (size_t)(row0 + r) * DIM + c0;
#pragma unroll
        for (int q = 0; q < 4; q++)
            *(short8*)&h16out[ob + q * 8] = *(const short8*)&buf[q * 8];
    }

    // ---- pool (batch sorted; run-length accumulate; 2 dims per lane) ----
    const int d0 = 2 * l;
    float p0 = 0.f, p1 = 0.f;
    int curg = gb[0];
    for (int r = 0; r < 16; r++) {
        int g = gb[r];
        if (g != curg) {
            atomicAdd(&pool_out[curg * OUT_COLS + layer * DIM + d0], p0);
            atomicAdd(&pool_out[curg * OUT_COLS + layer * DIM + d0 + 1], p1);
            p0 = p1 = 0.f;
            curg = g;
        }
        p0 += S[r][d0];
        p1 += S[r][d0 + 1];
    }
    atomicAdd(&pool_out[curg * OUT_COLS + layer * DIM + d0], p0);
    atomicAdd(&pool_out[curg * OUT_COLS + layer * DIM + d0 + 1], p1);
}

// ---------------- launch ----------------

extern "C" void kernel_launch(void* const* d_in, const int* in_sizes, int n_in,
                              void* d_out, int out_size, void* d_ws, size_t ws_size,
                              hipStream_t stream) {
    const float* x = (const float*)d_in[0];
    const int* ei = (const int*)d_in[1];
    const int* batch = (const int*)d_in[2];
    const float* W1 = (const float*)d_in[3];
    const float* b1 = (const float*)d_in[4];
    const float* W2 = (const float*)d_in[5];
    const float* b2 = (const float*)d_in[6];
    float* out = (float*)d_out;

    const int* src = ei;
    const int* dst = ei + N_EDGES;

    char* ws = (char*)d_ws;
    unsigned short* x16 = (unsigned short*)ws;                    // 12,800,000 B
    unsigned short* hA = (unsigned short*)(ws + 12800000);        // 12,800,000 B
    unsigned short* hB = (unsigned short*)(ws + 25600000);        // 12,800,000 B
    int* deg4 = (int*)(ws + 38400000);                            // 800,000 B
    _Float16* Wt = (_Float16*)(ws + 39200000);                    // 196,608 B
    unsigned short* elist = (unsigned short*)(ws + 39396608);     // 9,600,000 B -> 48,996,608 total

    hipMemsetAsync(d_out, 0, (size_t)out_size * sizeof(float), stream);
    hipMemsetAsync(deg4, 0, (size_t)N_NODES * SUBS * sizeof(int), stream);

    // fused preprocessing: adjacency fill | x->fp16 | W->fp16^T
    prep_kernel<<<FILL_NB + X2H_NB + WPREP_NB, 256, 0, stream>>>(
        src, dst, deg4, elist, x, x16, W1, W2, Wt);

    const int grid = N_NODES / 16;  // 3125, exact

    // layer 0: x16 -> hA ; layer 1: hA -> hB ; layer 2: hB -> (pool only)
    const unsigned short* hin[3] = {x16, hA, hB};
    unsigned short* hout[3] = {hA, hB, nullptr};
    for (int layer = 0; layer < N_LAYERS; layer++) {
        fused_layer_kernel<<<grid, 64, 0, stream>>>(
            hin[layer], deg4, elist, Wt + (size_t)layer * 2 * DIM * DIM,
            b1 + layer * DIM, b2 + layer * DIM, batch, hout[layer], out, layer,
            (layer < N_LAYERS - 1) ? 1 : 0);
    }
}